// Round 3
// baseline (382.678 us; speedup 1.0000x reference)
//
#include <hip/hip_runtime.h>

typedef unsigned short u16;
typedef unsigned int u32;
typedef __attribute__((ext_vector_type(8))) short bf16x8;
typedef __attribute__((ext_vector_type(4))) float f32x4;

#define DEVI __device__ __forceinline__

namespace {
constexpr int LQ_ = 20, LD_ = 512, D_ = 300;
constexpr int EQ_ = 5, ED_ = 10, KC_ = 10;
constexpr int QROWS = 62, DROWS = 1543;
constexpr int QSTR = 64, DSTR = 1600;      // padded row strides for qcat/dcat/sim
// xall row regions (row index base), each row = 320 bf16 (zero-padded 300..319)
constexpr int XDOC0 = 0;          // 64*512
constexpr int XQ0   = 32768;      // 64*20
constexpr int XQD0  = 34048;      // 320*20
constexpr int XDD0  = 40448;      // 640*20
constexpr int XNR   = 53248;
constexpr float MU_H[11] = {1.0f,0.9f,0.7f,0.5f,0.3f,0.1f,-0.1f,-0.3f,-0.5f,-0.7f,-0.9f};
}

__constant__ int P2QT_C[16] = {0,0,0,1,2,1,1,2,2,3,3,3,0,1,2,3};
__constant__ int P2DT_C[16] = {0,2,1,0,0,1,2,1,2,0,1,2,3,3,3,3};

DEVI u16 f2bf(float f){ union{float f;u32 u;} v; v.f=f; u32 r=(v.u+0x7fffu+((v.u>>16)&1u))>>16; return (u16)r; }
DEVI float bf2f(u16 h){ union{u32 u;float f;} v; v.u=((u32)h)<<16; return v.f; }

// ---------------- Weight pack: bf16 MFMA-fragment layout ----------------
__global__ __launch_bounds__(256) void k_wpack(const float* __restrict__ Wu, const float* __restrict__ Wb,
                                               const float* __restrict__ Wt, const float* __restrict__ Wd,
                                               u16* __restrict__ Wp){
  const int ts = blockIdx.x, ks = blockIdx.y;
  const float* W; int kk, tap;
  if(ts==0){W=Wu;kk=1;tap=0;}
  else if(ts<3){W=Wb;kk=2;tap=ts-1;}
  else if(ts<6){W=Wt;kk=3;tap=ts-3;}
  else {W=Wd;kk=5;tap=ts-6;}
  for(int idx=threadIdx.x; idx<4096; idx+=256){
    int n0=idx>>9, lane=(idx>>3)&63, j=idx&7;
    int col=lane&15, kg=lane>>4;
    int d=ks*32+kg*8+j, o=n0*16+col;
    float v = (d<300)? W[((long)o*kk + tap)*300 + d] : 0.f;
    Wp[(((long)(ts*8+n0)*10+ks)*64 + lane)*8 + j] = f2bf(v);
  }
}

// ---------------- One-shot gather: all token rows -> bf16 xall (row stride 320) ----------------
__global__ __launch_bounds__(256) void k_gather(const int* __restrict__ dwt, const int* __restrict__ qwt,
                                                const int* __restrict__ qet, const int* __restrict__ det,
                                                const float* __restrict__ emb, u16* __restrict__ xall){
  long idx = (long)blockIdx.x*256 + threadIdx.x;
  int row = (int)(idx/80), q = (int)(idx - (long)row*80);
  int tid;
  if(row < XQ0) tid = dwt[row];
  else if(row < XQD0) tid = qwt[row-XQ0];
  else if(row < XDD0) tid = qet[row-XQD0];
  else tid = det[row-XDD0];
  ushort4 o4;
  if(q < 75){
    float4 v = ((const float4*)(emb + (long)tid*D_))[q];
    o4.x=f2bf(v.x); o4.y=f2bf(v.y); o4.z=f2bf(v.z); o4.w=f2bf(v.w);
  } else { o4.x=0;o4.y=0;o4.z=0;o4.w=0; }
  *(ushort4*)(xall + (long)row*320 + q*4) = o4;
}

// ---------------- BOW phase A: partial sums from bf16 xall ----------------
__global__ __launch_bounds__(128) void k_bowpart(const u16* __restrict__ xall, float* __restrict__ partials){
  const int b=blockIdx.x, seg=blockIdx.y, side=blockIdx.z, t=threadIdx.x;
  float a0=0.f,a1=0.f,a2=0.f,a3=0.f;
  if(t<80){
    int nrow; long base;
    if(side==1){ nrow=64; base = ((long)b*LD_ + seg*64)*320; }
    else { nrow = (seg==0)? LQ_ : 0; base = ((long)XQ0 + b*LQ_)*320; }
    for(int r=0;r<nrow;r++){
      ushort4 v = *(const ushort4*)(xall + base + (long)r*320 + t*4);
      a0+=bf2f(v.x); a1+=bf2f(v.y); a2+=bf2f(v.z); a3+=bf2f(v.w);
    }
  }
  if(t<76){
    float4 o4={a0,a1,a2,a3};
    *(float4*)(partials + (((long)side*64 + b)*8 + seg)*304 + t*4) = o4;
  }
}

// ---------------- BOW phase B: reduce + matvec ----------------
__global__ __launch_bounds__(128) void k_bowmat(const float* __restrict__ partials,
                                                const float* __restrict__ bowW, const float* __restrict__ bowb,
                                                float* __restrict__ qbow, float* __restrict__ dbow){
  const int b=blockIdx.x, side=blockIdx.y, t=threadIdx.x;
  __shared__ float sv[304];
  const float* p = partials + ((long)side*64 + b)*8*304;
  for(int d=t; d<304; d+=128){
    float s=0.f;
    #pragma unroll
    for(int g=0;g<8;g++) s += p[g*304+d];
    sv[d]=s;
  }
  __syncthreads();
  float acc=0.f;
  const float* w = bowW + (long)t*D_;
  for(int d=0; d<D_; d++) acc += sv[d]*w[d];
  const float L = side? (float)LD_ : (float)LQ_;
  (side? dbow:qbow)[b*128+t] = acc + L*bowb[t];
}

// ---------------- Fused uni/bi/tri conv via MFMA (+bias+relu+l2norm, bf16 out) ----------------
__global__ __launch_bounds__(256) void k_conv_mfma(const u16* __restrict__ xall, int rowbase, int Ltok,
    const u16* __restrict__ Wp,
    const float* __restrict__ bu, const float* __restrict__ bb, const float* __restrict__ bt,
    u16* __restrict__ outp, long seqstride)
{
  const int seq=blockIdx.x, l0=blockIdx.y*64;
  const int t=threadIdx.x;
  __shared__ u16 xs[66*328];
  const int nrows = min(66, Ltok - l0);
  const u16* src = xall + ((long)(rowbase + seq*Ltok + l0))*320;
  for(int idx=t; idx<nrows*40; idx+=256){
    int r=idx/40, c=idx-r*40;
    *(bf16x8*)&xs[r*328 + c*8] = *(const bf16x8*)&src[(long)r*320 + c*8];
  }
  __syncthreads();
  const int lane=t&63, wave=t>>6;
  const int col16=lane&15, kg=lane>>4;
  for(int c=0;c<3;c++){
    const int base = (c==0)?0:((c==1)?Ltok:2*Ltok-1);
    const int Lout = Ltok-c;
    const int tb   = (c==0)?0:((c==1)?1:3);
    const float* bias = (c==0)?bu:((c==1)?bb:bt);
    f32x4 acc[8];
    #pragma unroll
    for(int n0=0;n0<8;n0++) acc[n0]=(f32x4){0.f,0.f,0.f,0.f};
    for(int i=0;i<=c;i++){
      const u16* xrow = &xs[(wave*16+col16+i)*328];
      for(int ks=0;ks<10;ks++){
        bf16x8 a = *(const bf16x8*)(xrow + ks*32 + kg*8);
        const u16* wpb = Wp + (((long)(tb+i)*8)*10 + (long)ks)*512 + lane*8;
        #pragma unroll
        for(int n0=0;n0<8;n0++){
          bf16x8 bfr = *(const bf16x8*)(wpb + (long)n0*10*512);
          acc[n0]=__builtin_amdgcn_mfma_f32_16x16x32_bf16(a,bfr,acc[n0],0,0,0);
        }
      }
    }
    float bv[8];
    #pragma unroll
    for(int n0=0;n0<8;n0++) bv[n0]=bias[n0*16+col16];
    float v[8][4], inv[4];
    #pragma unroll
    for(int reg=0;reg<4;reg++){
      float ss=0.f;
      #pragma unroll
      for(int n0=0;n0<8;n0++){
        float x = fmaxf(acc[n0][reg]+bv[n0], 0.f);
        v[n0][reg]=x; ss+=x*x;
      }
      ss+=__shfl_xor(ss,1); ss+=__shfl_xor(ss,2); ss+=__shfl_xor(ss,4); ss+=__shfl_xor(ss,8);
      inv[reg]=1.0f/fmaxf(sqrtf(ss),1e-10f);
    }
    #pragma unroll
    for(int reg=0;reg<4;reg++){
      const int p = l0 + wave*16 + kg*4 + reg;
      if(p<Lout){
        u16* ob = outp + (long)seq*seqstride + ((long)(base+p))*128;
        #pragma unroll
        for(int n0=0;n0<8;n0++) ob[n0*16+col16]=f2bf(v[n0][reg]*inv[reg]);
      }
    }
  }
}

// ---------------- Desc conv (k=5) via MFMA + fused max-pool, fp32 out ----------------
__global__ __launch_bounds__(256) void k_desc_mfma(const u16* __restrict__ xall, int rowbase, int nseq,
    const u16* __restrict__ Wp, const float* __restrict__ bd, float* __restrict__ dm)
{
  const int wave=threadIdx.x>>6, lane=threadIdx.x&63;
  const int seq=blockIdx.x*4+wave;
  __shared__ u16 xs[4][20*328];
  const int col16=lane&15, kg=lane>>4;
  if(seq<nseq){
    const u16* src = xall + ((long)(rowbase + seq*20))*320;
    for(int idx=lane; idx<20*40; idx+=64){
      int r=idx/40, c=idx-r*40;
      *(bf16x8*)&xs[wave][r*328 + c*8] = *(const bf16x8*)&src[(long)r*320 + c*8];
    }
  }
  __syncthreads();
  if(seq>=nseq) return;
  f32x4 acc[8];
  #pragma unroll
  for(int n0=0;n0<8;n0++) acc[n0]=(f32x4){0.f,0.f,0.f,0.f};
  for(int tap=0;tap<5;tap++){
    const u16* xrow=&xs[wave][(col16+tap)*328];
    for(int ks=0;ks<10;ks++){
      bf16x8 a=*(const bf16x8*)(xrow+ks*32+kg*8);
      const u16* wpb=Wp + (((long)(6+tap)*8)*10 + (long)ks)*512 + lane*8;
      #pragma unroll
      for(int n0=0;n0<8;n0++){
        bf16x8 bfr=*(const bf16x8*)(wpb + (long)n0*10*512);
        acc[n0]=__builtin_amdgcn_mfma_f32_16x16x32_bf16(a,bfr,acc[n0],0,0,0);
      }
    }
  }
  #pragma unroll
  for(int n0=0;n0<8;n0++){
    float bv=bd[n0*16+col16];
    float m=-1e30f;
    #pragma unroll
    for(int reg=0;reg<4;reg++) m=fmaxf(m, fmaxf(acc[n0][reg]+bv,0.f));
    m=fmaxf(m,__shfl_xor(m,16));
    m=fmaxf(m,__shfl_xor(m,32));
    if(kg==0) dm[(long)seq*128 + n0*16+col16]=m;
  }
}

// ---------------- Entity branch post: attention + combine + l2 ----------------
__global__ __launch_bounds__(256) void k_entpost(
    const int* __restrict__ qei, const int* __restrict__ qew,
    const int* __restrict__ dei, const int* __restrict__ dew,
    const float* __restrict__ qdm, const float* __restrict__ ddm,
    const float* __restrict__ qbow, const float* __restrict__ dbow,
    const float* __restrict__ ent, const float* __restrict__ car,
    u16* __restrict__ qcat, u16* __restrict__ dcat)
{
  const int e15 = blockIdx.x, b = blockIdx.y, t = threadIdx.x;
  const bool isq = (e15 < EQ_);
  const int e = isq? e15 : e15-EQ_;
  const float* dmx = isq? (qdm + (long)(b*EQ_+e)*128) : (ddm + (long)(b*ED_+e)*128);
  const float* bw = isq? (qbow + b*128) : (dbow + b*128);
  const int eid = isq? qei[b*EQ_+e] : dei[b*ED_+e];
  const int* carids = isq? (qew + b*EQ_*KC_ + e*KC_) : (dew + b*ED_*KC_ + e*KC_);
  u16* orow = isq? (qcat + ((long)b*QSTR + 57 + e)*128) : (dcat + ((long)b*DSTR + 1533 + e)*128);

  __shared__ float carS[KC_*128];
  __shared__ float sc[KC_], att[KC_];
  __shared__ float red[4];
  for(int idx=t; idx<KC_*128; idx+=256){
    int j = idx>>7, c = idx&127;
    carS[j*128+c] = car[(long)carids[j]*128 + c];
  }
  __syncthreads();
  {
    const int j = t>>4, l16 = t&15;
    if(j < KC_){
      float s=0.f;
      for(int c=l16;c<128;c+=16) s += bw[c]*carS[j*128+c];
      s += __shfl_xor(s,1); s += __shfl_xor(s,2); s += __shfl_xor(s,4); s += __shfl_xor(s,8);
      if(l16==0) sc[j]=s;
    }
  }
  __syncthreads();
  if(t==0){
    float m=-1e30f;
    for(int x=0;x<KC_;x++) m = fmaxf(m, sc[x]);
    float ssum=0.f;
    for(int x=0;x<KC_;x++){ float e2=__expf(sc[x]-m); att[x]=e2; ssum+=e2; }
    float rs = 1.0f/ssum;
    for(int x=0;x<KC_;x++) att[x]*=rs;
  }
  __syncthreads();
  float val=0.f;
  if(t<128){
    float ew=0.f;
    for(int x=0;x<KC_;x++) ew += att[x]*carS[x*128+t];
    val = ent[(long)eid*128+t] + dmx[t] + ew;
  }
  float ss = val*val;
  ss += __shfl_xor(ss,1); ss += __shfl_xor(ss,2); ss += __shfl_xor(ss,4);
  ss += __shfl_xor(ss,8); ss += __shfl_xor(ss,16); ss += __shfl_xor(ss,32);
  if((t&63)==0) red[t>>6]=ss;
  __syncthreads();
  if(t<128){
    float nv = 1.0f/fmaxf(sqrtf(red[0]+red[1]),1e-10f);
    orow[t] = f2bf(val*nv);
  }
}

// ---------------- sim = Qcat . Dcat^T via MFMA ----------------
__global__ __launch_bounds__(256) void k_sim_mfma(const u16* __restrict__ qcat, const u16* __restrict__ dcat,
                                                  float* __restrict__ sim){
  const int b=blockIdx.x, nb=blockIdx.y, t=threadIdx.x;
  __shared__ u16 Qs[64*136];
  __shared__ u16 Ds[64*136];
  const u16* qbase = qcat + (long)b*QSTR*128;
  const u16* dbase = dcat + ((long)b*DSTR + nb*64)*128;
  for(int idx=t; idx<1024; idx+=256){
    int r=idx>>4, c8=(idx&15)*8;
    *(bf16x8*)&Qs[r*136+c8] = *(const bf16x8*)&qbase[(long)r*128+c8];
    *(bf16x8*)&Ds[r*136+c8] = *(const bf16x8*)&dbase[(long)r*128+c8];
  }
  __syncthreads();
  const int lane=t&63, wave=t>>6, col16=lane&15, kg=lane>>4;
  f32x4 acc[4];
  #pragma unroll
  for(int n0=0;n0<4;n0++) acc[n0]=(f32x4){0.f,0.f,0.f,0.f};
  #pragma unroll
  for(int ks=0;ks<4;ks++){
    bf16x8 a=*(const bf16x8*)&Qs[(wave*16+col16)*136 + ks*32 + kg*8];
    #pragma unroll
    for(int n0=0;n0<4;n0++){
      bf16x8 bfr=*(const bf16x8*)&Ds[(n0*16+col16)*136 + ks*32 + kg*8];
      acc[n0]=__builtin_amdgcn_mfma_f32_16x16x32_bf16(a,bfr,acc[n0],0,0,0);
    }
  }
  #pragma unroll
  for(int n0=0;n0<4;n0++){
    const int col = nb*64 + n0*16 + col16;
    #pragma unroll
    for(int reg=0;reg<4;reg++){
      const int qr = wave*16 + kg*4 + reg;
      if(qr<QROWS) sim[((long)b*QROWS+qr)*DSTR + col]=acc[n0][reg];
    }
  }
}

// ---------------- RBF pools ----------------
__global__ __launch_bounds__(256) void k_gauss(const float* __restrict__ sim, const float* __restrict__ dwm,
                                               const float* __restrict__ dem, float* __restrict__ S){
  const int b = blockIdx.x, qr = blockIdx.y, t = threadIdx.x;
  const float* srow = sim + ((long)b*QROWS + qr)*DSTR;
  float* Sout = S + ((long)b*QROWS + qr)*44;
  __shared__ float wsum[4][11];
  constexpr int SB[5] = {0,512,1023,1533,1543};
  #pragma unroll
  for(int s=0;s<4;s++){
    float a[11];
    #pragma unroll
    for(int m=0;m<11;m++) a[m]=0.f;
    for(int dr = SB[s]+t; dr < SB[s+1]; dr += 256){
      float sv = srow[dr];
      int pos = dr - SB[s];
      float md = (s<3)? dwm[b*LD_+pos] : dem[b*ED_+pos];
      float d1 = sv - 1.0f;
      a[0] += md*__expf(-500000.0f*d1*d1);
      #pragma unroll
      for(int m=1;m<11;m++){ float dm = sv - MU_H[m]; a[m] += md*__expf(-50.0f*dm*dm); }
    }
    #pragma unroll
    for(int m=0;m<11;m++){
      float v=a[m];
      v+=__shfl_xor(v,1); v+=__shfl_xor(v,2); v+=__shfl_xor(v,4);
      v+=__shfl_xor(v,8); v+=__shfl_xor(v,16); v+=__shfl_xor(v,32);
      if((t&63)==0) wsum[t>>6][m]=v;
    }
    __syncthreads();
    if(t<11) Sout[s*11+t] = wsum[0][t]+wsum[1][t]+wsum[2][t]+wsum[3][t];
    __syncthreads();
  }
}

// ---------------- log-pool + dense + tanh ----------------
__global__ __launch_bounds__(256) void k_feats(const float* __restrict__ S, const float* __restrict__ qwm,
                                               const float* __restrict__ qem, const float* __restrict__ dfW,
                                               const float* __restrict__ dfb, float* __restrict__ out){
  const int b = blockIdx.x, t = threadIdx.x;
  __shared__ float fsh[176];
  __shared__ float red[4];
  if(t<176){
    const int pool = t/11, m = t - pool*11;
    const int qt = P2QT_C[pool], dt = P2DT_C[pool];
    const int qlo = (qt==0)?0:((qt==1)?20:((qt==2)?39:57));
    const int qn  = (qt==0)?20:((qt==1)?19:((qt==2)?18:5));
    const float* Sb = S + ((long)b*QROWS)*44 + dt*11 + m;
    float f = 0.f;
    for(int r=0;r<qn;r++){
      float mq = (qt<3)? qwm[b*LQ_+r] : qem[b*EQ_+r];
      float sv = Sb[(long)(qlo+r)*44];
      f += logf(fmaxf(sv,1e-10f))*0.01f*mq;
    }
    fsh[t] = f;
  }
  __syncthreads();
  float v = (t<176)? fsh[t]*dfW[t] : 0.f;
  v += __shfl_xor(v,1); v += __shfl_xor(v,2); v += __shfl_xor(v,4);
  v += __shfl_xor(v,8); v += __shfl_xor(v,16); v += __shfl_xor(v,32);
  if((t&63)==0) red[t>>6]=v;
  __syncthreads();
  if(t==0) out[b] = tanhf(red[0]+red[1]+red[2]+red[3] + dfb[0]);
}

extern "C" void kernel_launch(void* const* d_in, const int* in_sizes, int n_in,
                              void* d_out, int out_size, void* d_ws, size_t ws_size,
                              hipStream_t stream)
{
  const int*   qwt=(const int*)d_in[0];
  const float* qwm=(const float*)d_in[1];
  const int*   qei=(const int*)d_in[2];
  const int*   qet=(const int*)d_in[3];
  const int*   qew=(const int*)d_in[4];
  const float* qem=(const float*)d_in[5];
  const int*   dwt=(const int*)d_in[6];
  const float* dwm=(const float*)d_in[7];
  const int*   dei=(const int*)d_in[8];
  const int*   det=(const int*)d_in[9];
  const int*   dew=(const int*)d_in[10];
  const float* dem=(const float*)d_in[11];
  const float* emb=(const float*)d_in[12];
  const float* ent=(const float*)d_in[13];
  const float* car=(const float*)d_in[14];
  const float* bowW=(const float*)d_in[15];
  const float* bowb=(const float*)d_in[16];
  const float* Wu=(const float*)d_in[17];
  const float* bu=(const float*)d_in[18];
  const float* Wb=(const float*)d_in[19];
  const float* bb=(const float*)d_in[20];
  const float* Wt=(const float*)d_in[21];
  const float* bt=(const float*)d_in[22];
  const float* Wd=(const float*)d_in[23];
  const float* bd=(const float*)d_in[24];
  const float* dfW=(const float*)d_in[25];
  const float* dfb=(const float*)d_in[26];
  float* out=(float*)d_out;

  char* ws=(char*)d_ws;
  size_t off=0;
  auto A=[&](size_t n){ size_t r=off; off=(off+n+255)&~(size_t)255; return r; };
  u16* Wp     = (u16*)(ws + A((size_t)11*8*10*64*8*2));
  u16* dcat   = (u16*)(ws + A((size_t)64*DSTR*128*2));
  u16* qcat   = (u16*)(ws + A((size_t)64*QSTR*128*2));
  float* qdm  = (float*)(ws + A((size_t)320*128*4));
  float* ddm  = (float*)(ws + A((size_t)640*128*4));
  float* parts= (float*)(ws + A((size_t)2*64*8*304*4));
  float* qbow = (float*)(ws + A((size_t)64*128*4));
  float* dbow = (float*)(ws + A((size_t)64*128*4));
  // union: xall (gather staging, used through conv/desc/bow) overlaps simb (written later)
  size_t ubase = A((size_t)XNR*320*2 > (size_t)64*QROWS*DSTR*4 ? (size_t)XNR*320*2 : (size_t)64*QROWS*DSTR*4);
  u16*   xall = (u16*)(ws + ubase);
  float* simb = (float*)(ws + ubase);
  float* Sbuf = (float*)(ws + A((size_t)64*QROWS*44*4));
  if(off > ws_size) return;

  k_wpack<<<dim3(11,10),256,0,stream>>>(Wu,Wb,Wt,Wd,Wp);
  k_gather<<<(XNR*80)/256,256,0,stream>>>(dwt,qwt,qet,det,emb,xall);
  k_bowpart<<<dim3(64,8,2),128,0,stream>>>(xall,parts);
  k_bowmat<<<dim3(64,2),128,0,stream>>>(parts,bowW,bowb,qbow,dbow);

  k_conv_mfma<<<dim3(64,8),256,0,stream>>>(xall,XDOC0,LD_,Wp,bu,bb,bt,dcat,(long)DSTR*128);
  k_conv_mfma<<<dim3(64,1),256,0,stream>>>(xall,XQ0,LQ_,Wp,bu,bb,bt,qcat,(long)QSTR*128);
  k_desc_mfma<<<80,256,0,stream>>>(xall,XQD0,320,Wp,bd,qdm);
  k_desc_mfma<<<160,256,0,stream>>>(xall,XDD0,640,Wp,bd,ddm);

  k_entpost<<<dim3(15,64),256,0,stream>>>(qei,qew,dei,dew,qdm,ddm,qbow,dbow,ent,car,qcat,dcat);
  k_sim_mfma<<<dim3(64,25),256,0,stream>>>(qcat,dcat,simb);
  k_gauss<<<dim3(64,QROWS),256,0,stream>>>(simb,dwm,dem,Sbuf);
  k_feats<<<64,256,0,stream>>>(Sbuf,qwm,qem,dfW,dfb,out);
}

// Round 5
// 200.516 us; speedup vs baseline: 1.9085x; 1.9085x over previous
//
#include <hip/hip_runtime.h>

typedef unsigned short u16;
typedef unsigned int u32;
typedef __attribute__((ext_vector_type(8))) short bf16x8;
typedef __attribute__((ext_vector_type(4))) float f32x4;

#define DEVI __device__ __forceinline__

namespace {
constexpr int LQ_ = 20, LD_ = 512, D_ = 300;
constexpr int EQ_ = 5, ED_ = 10, KC_ = 10;
constexpr int QROWS = 62, DROWS = 1543;
constexpr int QSTR = 64, DSTR = 1600;      // padded row strides for qcat/dcat/sim
// xall row regions (row index base), each row = 320 bf16 (zero-padded 300..319)
constexpr int XDOC0 = 0;          // 64*512
constexpr int XQ0   = 32768;      // 64*20
constexpr int XQD0  = 34048;      // 320*20
constexpr int XDD0  = 40448;      // 640*20
constexpr int XNR   = 53248;
constexpr float MU_H[11] = {1.0f,0.9f,0.7f,0.5f,0.3f,0.1f,-0.1f,-0.3f,-0.5f,-0.7f,-0.9f};
}

__constant__ int P2QT_C[16] = {0,0,0,1,2,1,1,2,2,3,3,3,0,1,2,3};
__constant__ int P2DT_C[16] = {0,2,1,0,0,1,2,1,2,0,1,2,3,3,3,3};

DEVI u16 f2bf(float f){ union{float f;u32 u;} v; v.f=f; u32 r=(v.u+0x7fffu+((v.u>>16)&1u))>>16; return (u16)r; }
DEVI float bf2f(u16 h){ union{u32 u;float f;} v; v.u=((u32)h)<<16; return v.f; }

// ---------------- Weight pack: bf16 MFMA-fragment layout ----------------
// Wp[((ts*8+n0)*10+ks)*64+lane][8]; lane=kg*16+col ; val=W[o=n0*16+col][tap][d=ks*32+kg*8+j]
__global__ __launch_bounds__(256) void k_wpack(const float* __restrict__ Wu, const float* __restrict__ Wb,
                                               const float* __restrict__ Wt, const float* __restrict__ Wd,
                                               u16* __restrict__ Wp){
  const int ts = blockIdx.x, ks = blockIdx.y;
  const float* W; int kk, tap;
  if(ts==0){W=Wu;kk=1;tap=0;}
  else if(ts<3){W=Wb;kk=2;tap=ts-1;}
  else if(ts<6){W=Wt;kk=3;tap=ts-3;}
  else {W=Wd;kk=5;tap=ts-6;}
  for(int idx=threadIdx.x; idx<4096; idx+=256){
    int n0=idx>>9, lane=(idx>>3)&63, j=idx&7;
    int col=lane&15, kg=lane>>4;
    int d=ks*32+kg*8+j, o=n0*16+col;
    float v = (d<300)? W[((long)o*kk + tap)*300 + d] : 0.f;
    Wp[(((long)(ts*8+n0)*10+ks)*64 + lane)*8 + j] = f2bf(v);
  }
}

// ---------------- One-shot gather: all token rows -> bf16 xall (row stride 320) ----------------
__global__ __launch_bounds__(256) void k_gather(const int* __restrict__ dwt, const int* __restrict__ qwt,
                                                const int* __restrict__ qet, const int* __restrict__ det,
                                                const float* __restrict__ emb, u16* __restrict__ xall){
  long idx = (long)blockIdx.x*256 + threadIdx.x;
  int row = (int)(idx/80), q = (int)(idx - (long)row*80);
  int tid;
  if(row < XQ0) tid = dwt[row];
  else if(row < XQD0) tid = qwt[row-XQ0];
  else if(row < XDD0) tid = qet[row-XQD0];
  else tid = det[row-XDD0];
  ushort4 o4;
  if(q < 75){
    float4 v = ((const float4*)(emb + (long)tid*D_))[q];
    o4.x=f2bf(v.x); o4.y=f2bf(v.y); o4.z=f2bf(v.z); o4.w=f2bf(v.w);
  } else { o4.x=0;o4.y=0;o4.z=0;o4.w=0; }
  *(ushort4*)(xall + (long)row*320 + q*4) = o4;
}

// ---------------- BOW phase A: partial sums from bf16 xall ----------------
__global__ __launch_bounds__(128) void k_bowpart(const u16* __restrict__ xall, float* __restrict__ partials){
  const int b=blockIdx.x, seg=blockIdx.y, side=blockIdx.z, t=threadIdx.x;
  float a0=0.f,a1=0.f,a2=0.f,a3=0.f;
  if(t<80){
    int nrow; long base;
    if(side==1){ nrow=64; base = ((long)b*LD_ + seg*64)*320; }
    else { nrow = (seg==0)? LQ_ : 0; base = ((long)XQ0 + b*LQ_)*320; }
    for(int r=0;r<nrow;r++){
      ushort4 v = *(const ushort4*)(xall + base + (long)r*320 + t*4);
      a0+=bf2f(v.x); a1+=bf2f(v.y); a2+=bf2f(v.z); a3+=bf2f(v.w);
    }
  }
  if(t<76){
    float4 o4={a0,a1,a2,a3};
    *(float4*)(partials + (((long)side*64 + b)*8 + seg)*304 + t*4) = o4;
  }
}

// ---------------- BOW phase B: reduce + matvec ----------------
__global__ __launch_bounds__(128) void k_bowmat(const float* __restrict__ partials,
                                                const float* __restrict__ bowW, const float* __restrict__ bowb,
                                                float* __restrict__ qbow, float* __restrict__ dbow){
  const int b=blockIdx.x, side=blockIdx.y, t=threadIdx.x;
  __shared__ float sv[304];
  const float* p = partials + ((long)side*64 + b)*8*304;
  for(int d=t; d<304; d+=128){
    float s=0.f;
    #pragma unroll
    for(int g=0;g<8;g++) s += p[g*304+d];
    sv[d]=s;
  }
  __syncthreads();
  float acc=0.f;
  const float* w = bowW + (long)t*D_;
  for(int d=0; d<D_; d++) acc += sv[d]*w[d];
  const float L = side? (float)LD_ : (float)LQ_;
  (side? dbow:qbow)[b*128+t] = acc + L*bowb[t];
}

// ---------------- uni/bi/tri conv via MFMA, weights-in-registers, 8-wave blocks ----------------
// wave w owns channel group n0=w. Weights loaded once per K-half; A streams from LDS.
__global__ __launch_bounds__(512) void k_conv_mfma(const u16* __restrict__ xall, int rowbase, int Ltok,
    const u16* __restrict__ Wp,
    const float* __restrict__ bu, const float* __restrict__ bb, const float* __restrict__ bt,
    u16* __restrict__ outp, long seqstride)
{
  const int seq=blockIdx.x, l0=blockIdx.y*64;
  const int t=threadIdx.x;
  __shared__ u16 xs[66*328];
  __shared__ float ot[64*130];
  const int nrows = min(66, Ltok - l0);
  const u16* src = xall + ((long)(rowbase + seq*Ltok + l0))*320;
  {
    const bf16x8 z = {0,0,0,0,0,0,0,0};
    for(int idx=t; idx<66*40; idx+=512){
      int r=idx/40, cc=idx-r*40;
      bf16x8 v = *(const bf16x8*)&src[(long)r*320 + cc*8];
      *(bf16x8*)&xs[r*328 + cc*8] = (r<nrows)? v : z;
    }
  }
  __syncthreads();
  const int lane=t&63, wave=t>>6;
  const int col16=lane&15, kg=lane>>4;
  #pragma unroll
  for(int c=0;c<3;c++){
    const int tb = (c==0)?0:((c==1)?1:3);
    const int base = (c==0)?0:((c==1)?Ltok:2*Ltok-1);
    const float* bias = (c==0)?bu:((c==1)?bb:bt);
    f32x4 acc4[4];
    #pragma unroll
    for(int mt=0;mt<4;mt++) acc4[mt]=(f32x4){0.f,0.f,0.f,0.f};
    #pragma unroll
    for(int h=0;h<2;h++){
      bf16x8 wf[15];
      #pragma unroll
      for(int i=0;i<=c;i++)
        #pragma unroll
        for(int k5=0;k5<5;k5++)
          wf[i*5+k5] = *(const bf16x8*)(Wp + (((long)((tb+i)*8 + wave)*10) + h*5 + k5)*512 + lane*8);
      #pragma unroll
      for(int mt=0;mt<4;mt++){
        #pragma unroll
        for(int i=0;i<=c;i++){
          const u16* xrow = &xs[(mt*16 + col16 + i)*328 + h*160];
          #pragma unroll
          for(int k5=0;k5<5;k5++){
            bf16x8 a = *(const bf16x8*)(xrow + k5*32 + kg*8);
            acc4[mt]=__builtin_amdgcn_mfma_f32_16x16x32_bf16(a,wf[i*5+k5],acc4[mt],0,0,0);
          }
        }
      }
    }
    const float bv = bias[wave*16+col16];
    #pragma unroll
    for(int mt=0;mt<4;mt++)
      #pragma unroll
      for(int reg=0;reg<4;reg++)
        ot[(mt*16+kg*4+reg)*130 + wave*16+col16] = fmaxf(acc4[mt][reg]+bv, 0.f);
    __syncthreads();
    // l2-norm + coalesced store
    {
      const int p = t>>3, j = t&7;
      const int nv = min(64, (Ltok - c) - l0);
      float ss=0.f;
      if(p<nv){
        #pragma unroll
        for(int k=0;k<16;k++){ float v = ot[p*130 + j + 8*k]; ss += v*v; }
      }
      ss += __shfl_xor(ss,1); ss += __shfl_xor(ss,2); ss += __shfl_xor(ss,4);
      if(p<nv){
        float inv = 1.0f/fmaxf(sqrtf(ss),1e-10f);
        u16* ob = outp + (long)seq*seqstride + ((long)(base + l0 + p))*128 + j*16;
        #pragma unroll
        for(int hh=0;hh<2;hh++){
          bf16x8 o8;
          #pragma unroll
          for(int e=0;e<8;e++) o8[e] = (short)f2bf(ot[p*130 + j*16 + hh*8 + e]*inv);
          *(bf16x8*)(ob + hh*8) = o8;
        }
      }
    }
    __syncthreads();
  }
}

// ---------------- Desc conv (k=5) via MFMA, weights-in-registers + fused max-pool ----------------
__global__ __launch_bounds__(512) void k_desc_mfma(const u16* __restrict__ xall, int rowbase,
    const u16* __restrict__ Wp, const float* __restrict__ bd, float* __restrict__ dm)
{
  const int t=threadIdx.x, lane=t&63, wave=t>>6;
  const int col16=lane&15, kg=lane>>4;
  __shared__ u16 xs4[4*20*328];
  {
    const int s0 = blockIdx.x*4;
    for(int idx=t; idx<4*20*40; idx+=512){
      int s=idx/800, rem=idx-s*800, r=rem/40, cc=rem-r*40;
      *(bf16x8*)&xs4[(s*20+r)*328 + cc*8] =
        *(const bf16x8*)&xall[((long)(rowbase + (s0+s)*20 + r))*320 + cc*8];
    }
  }
  __syncthreads();
  f32x4 acc4[4];
  #pragma unroll
  for(int s=0;s<4;s++) acc4[s]=(f32x4){0.f,0.f,0.f,0.f};
  #pragma unroll
  for(int h=0;h<2;h++){
    bf16x8 wf[25];
    #pragma unroll
    for(int tap=0;tap<5;tap++)
      #pragma unroll
      for(int k5=0;k5<5;k5++)
        wf[tap*5+k5] = *(const bf16x8*)(Wp + (((long)((6+tap)*8 + wave)*10) + h*5 + k5)*512 + lane*8);
    #pragma unroll
    for(int s=0;s<4;s++){
      #pragma unroll
      for(int tap=0;tap<5;tap++){
        const u16* xrow = &xs4[(s*20 + col16 + tap)*328 + h*160];
        #pragma unroll
        for(int k5=0;k5<5;k5++){
          bf16x8 a = *(const bf16x8*)(xrow + k5*32 + kg*8);
          acc4[s]=__builtin_amdgcn_mfma_f32_16x16x32_bf16(a,wf[tap*5+k5],acc4[s],0,0,0);
        }
      }
    }
  }
  const float bv = bd[wave*16+col16];
  #pragma unroll
  for(int s=0;s<4;s++){
    float m=-1e30f;
    #pragma unroll
    for(int reg=0;reg<4;reg++) m=fmaxf(m, acc4[s][reg]+bv);
    m=fmaxf(m,__shfl_xor(m,16));
    m=fmaxf(m,__shfl_xor(m,32));
    m=fmaxf(m,0.f);
    if(kg==0) dm[(long)(blockIdx.x*4+s)*128 + wave*16+col16]=m;
  }
}

// ---------------- Entity branch post: attention + combine + l2 ----------------
__global__ __launch_bounds__(256) void k_entpost(
    const int* __restrict__ qei, const int* __restrict__ qew,
    const int* __restrict__ dei, const int* __restrict__ dew,
    const float* __restrict__ qdm, const float* __restrict__ ddm,
    const float* __restrict__ qbow, const float* __restrict__ dbow,
    const float* __restrict__ ent, const float* __restrict__ car,
    u16* __restrict__ qcat, u16* __restrict__ dcat)
{
  const int e15 = blockIdx.x, b = blockIdx.y, t = threadIdx.x;
  const bool isq = (e15 < EQ_);
  const int e = isq? e15 : e15-EQ_;
  const float* dmx = isq? (qdm + (long)(b*EQ_+e)*128) : (ddm + (long)(b*ED_+e)*128);
  const float* bw = isq? (qbow + b*128) : (dbow + b*128);
  const int eid = isq? qei[b*EQ_+e] : dei[b*ED_+e];
  const int* carids = isq? (qew + b*EQ_*KC_ + e*KC_) : (dew + b*ED_*KC_ + e*KC_);
  u16* orow = isq? (qcat + ((long)b*QSTR + 57 + e)*128) : (dcat + ((long)b*DSTR + 1533 + e)*128);

  __shared__ float carS[KC_*128];
  __shared__ float sc[KC_], att[KC_];
  __shared__ float red[4];
  for(int idx=t; idx<KC_*128; idx+=256){
    int j = idx>>7, c = idx&127;
    carS[j*128+c] = car[(long)carids[j]*128 + c];
  }
  __syncthreads();
  {
    const int j = t>>4, l16 = t&15;
    if(j < KC_){
      float s=0.f;
      for(int c=l16;c<128;c+=16) s += bw[c]*carS[j*128+c];
      s += __shfl_xor(s,1); s += __shfl_xor(s,2); s += __shfl_xor(s,4); s += __shfl_xor(s,8);
      if(l16==0) sc[j]=s;
    }
  }
  __syncthreads();
  if(t==0){
    float m=-1e30f;
    for(int x=0;x<KC_;x++) m = fmaxf(m, sc[x]);
    float ssum=0.f;
    for(int x=0;x<KC_;x++){ float e2=__expf(sc[x]-m); att[x]=e2; ssum+=e2; }
    float rs = 1.0f/ssum;
    for(int x=0;x<KC_;x++) att[x]*=rs;
  }
  __syncthreads();
  float val=0.f;
  if(t<128){
    float ew=0.f;
    for(int x=0;x<KC_;x++) ew += att[x]*carS[x*128+t];
    val = ent[(long)eid*128+t] + dmx[t] + ew;
  }
  float ss = val*val;
  ss += __shfl_xor(ss,1); ss += __shfl_xor(ss,2); ss += __shfl_xor(ss,4);
  ss += __shfl_xor(ss,8); ss += __shfl_xor(ss,16); ss += __shfl_xor(ss,32);
  if((t&63)==0) red[t>>6]=ss;
  __syncthreads();
  if(t<128){
    float nv = 1.0f/fmaxf(sqrtf(red[0]+red[1]),1e-10f);
    orow[t] = f2bf(val*nv);
  }
}

// ---------------- sim = Qcat . Dcat^T via MFMA ----------------
__global__ __launch_bounds__(256) void k_sim_mfma(const u16* __restrict__ qcat, const u16* __restrict__ dcat,
                                                  float* __restrict__ sim){
  const int b=blockIdx.x, nb=blockIdx.y, t=threadIdx.x;
  __shared__ u16 Qs[64*136];
  __shared__ u16 Ds[64*136];
  const u16* qbase = qcat + (long)b*QSTR*128;
  const u16* dbase = dcat + ((long)b*DSTR + nb*64)*128;
  for(int idx=t; idx<1024; idx+=256){
    int r=idx>>4, c8=(idx&15)*8;
    *(bf16x8*)&Qs[r*136+c8] = *(const bf16x8*)&qbase[(long)r*128+c8];
    *(bf16x8*)&Ds[r*136+c8] = *(const bf16x8*)&dbase[(long)r*128+c8];
  }
  __syncthreads();
  const int lane=t&63, wave=t>>6, col16=lane&15, kg=lane>>4;
  f32x4 acc[4];
  #pragma unroll
  for(int n0=0;n0<4;n0++) acc[n0]=(f32x4){0.f,0.f,0.f,0.f};
  #pragma unroll
  for(int ks=0;ks<4;ks++){
    bf16x8 a=*(const bf16x8*)&Qs[(wave*16+col16)*136 + ks*32 + kg*8];
    #pragma unroll
    for(int n0=0;n0<4;n0++){
      bf16x8 bfr=*(const bf16x8*)&Ds[(n0*16+col16)*136 + ks*32 + kg*8];
      acc[n0]=__builtin_amdgcn_mfma_f32_16x16x32_bf16(a,bfr,acc[n0],0,0,0);
    }
  }
  #pragma unroll
  for(int n0=0;n0<4;n0++){
    const int col = nb*64 + n0*16 + col16;
    #pragma unroll
    for(int reg=0;reg<4;reg++){
      const int qr = wave*16 + kg*4 + reg;
      if(qr<QROWS) sim[((long)b*QROWS+qr)*DSTR + col]=acc[n0][reg];
    }
  }
}

// ---------------- RBF pools ----------------
__global__ __launch_bounds__(256) void k_gauss(const float* __restrict__ sim, const float* __restrict__ dwm,
                                               const float* __restrict__ dem, float* __restrict__ S){
  const int b = blockIdx.x, qr = blockIdx.y, t = threadIdx.x;
  const float* srow = sim + ((long)b*QROWS + qr)*DSTR;
  float* Sout = S + ((long)b*QROWS + qr)*44;
  __shared__ float wsum[4][11];
  constexpr int SB[5] = {0,512,1023,1533,1543};
  #pragma unroll
  for(int s=0;s<4;s++){
    float a[11];
    #pragma unroll
    for(int m=0;m<11;m++) a[m]=0.f;
    for(int dr = SB[s]+t; dr < SB[s+1]; dr += 256){
      float sv = srow[dr];
      int pos = dr - SB[s];
      float md = (s<3)? dwm[b*LD_+pos] : dem[b*ED_+pos];
      float d1 = sv - 1.0f;
      a[0] += md*__expf(-500000.0f*d1*d1);
      #pragma unroll
      for(int m=1;m<11;m++){ float dm = sv - MU_H[m]; a[m] += md*__expf(-50.0f*dm*dm); }
    }
    #pragma unroll
    for(int m=0;m<11;m++){
      float v=a[m];
      v+=__shfl_xor(v,1); v+=__shfl_xor(v,2); v+=__shfl_xor(v,4);
      v+=__shfl_xor(v,8); v+=__shfl_xor(v,16); v+=__shfl_xor(v,32);
      if((t&63)==0) wsum[t>>6][m]=v;
    }
    __syncthreads();
    if(t<11) Sout[s*11+t] = wsum[0][t]+wsum[1][t]+wsum[2][t]+wsum[3][t];
    __syncthreads();
  }
}

// ---------------- log-pool + dense + tanh ----------------
__global__ __launch_bounds__(256) void k_feats(const float* __restrict__ S, const float* __restrict__ qwm,
                                               const float* __restrict__ qem, const float* __restrict__ dfW,
                                               const float* __restrict__ dfb, float* __restrict__ out){
  const int b = blockIdx.x, t = threadIdx.x;
  __shared__ float fsh[176];
  __shared__ float red[4];
  if(t<176){
    const int pool = t/11, m = t - pool*11;
    const int qt = P2QT_C[pool], dt = P2DT_C[pool];
    const int qlo = (qt==0)?0:((qt==1)?20:((qt==2)?39:57));
    const int qn  = (qt==0)?20:((qt==1)?19:((qt==2)?18:5));
    const float* Sb = S + ((long)b*QROWS)*44 + dt*11 + m;
    float f = 0.f;
    for(int r=0;r<qn;r++){
      float mq = (qt<3)? qwm[b*LQ_+r] : qem[b*EQ_+r];
      float sv = Sb[(long)(qlo+r)*44];
      f += logf(fmaxf(sv,1e-10f))*0.01f*mq;
    }
    fsh[t] = f;
  }
  __syncthreads();
  float v = (t<176)? fsh[t]*dfW[t] : 0.f;
  v += __shfl_xor(v,1); v += __shfl_xor(v,2); v += __shfl_xor(v,4);
  v += __shfl_xor(v,8); v += __shfl_xor(v,16); v += __shfl_xor(v,32);
  if((t&63)==0) red[t>>6]=v;
  __syncthreads();
  if(t==0) out[b] = tanhf(red[0]+red[1]+red[2]+red[3] + dfb[0]);
}

extern "C" void kernel_launch(void* const* d_in, const int* in_sizes, int n_in,
                              void* d_out, int out_size, void* d_ws, size_t ws_size,
                              hipStream_t stream)
{
  const int*   qwt=(const int*)d_in[0];
  const float* qwm=(const float*)d_in[1];
  const int*   qei=(const int*)d_in[2];
  const int*   qet=(const int*)d_in[3];
  const int*   qew=(const int*)d_in[4];
  const float* qem=(const float*)d_in[5];
  const int*   dwt=(const int*)d_in[6];
  const float* dwm=(const float*)d_in[7];
  const int*   dei=(const int*)d_in[8];
  const int*   det=(const int*)d_in[9];
  const int*   dew=(const int*)d_in[10];
  const float* dem=(const float*)d_in[11];
  const float* emb=(const float*)d_in[12];
  const float* ent=(const float*)d_in[13];
  const float* car=(const float*)d_in[14];
  const float* bowW=(const float*)d_in[15];
  const float* bowb=(const float*)d_in[16];
  const float* Wu=(const float*)d_in[17];
  const float* bu=(const float*)d_in[18];
  const float* Wb=(const float*)d_in[19];
  const float* bb=(const float*)d_in[20];
  const float* Wt=(const float*)d_in[21];
  const float* bt=(const float*)d_in[22];
  const float* Wd=(const float*)d_in[23];
  const float* bd=(const float*)d_in[24];
  const float* dfW=(const float*)d_in[25];
  const float* dfb=(const float*)d_in[26];
  float* out=(float*)d_out;

  char* ws=(char*)d_ws;
  size_t off=0;
  auto A=[&](size_t n){ size_t r=off; off=(off+n+255)&~(size_t)255; return r; };
  u16* Wp     = (u16*)(ws + A((size_t)11*8*10*64*8*2));
  u16* dcat   = (u16*)(ws + A((size_t)64*DSTR*128*2));
  u16* qcat   = (u16*)(ws + A((size_t)64*QSTR*128*2));
  float* qdm  = (float*)(ws + A((size_t)320*128*4));
  float* ddm  = (float*)(ws + A((size_t)640*128*4));
  float* parts= (float*)(ws + A((size_t)2*64*8*304*4));
  float* qbow = (float*)(ws + A((size_t)64*128*4));
  float* dbow = (float*)(ws + A((size_t)64*128*4));
  // union: xall (gather staging, used through conv/desc/bow) overlaps simb (written later)
  size_t ubase = A((size_t)XNR*320*2 > (size_t)64*QROWS*DSTR*4 ? (size_t)XNR*320*2 : (size_t)64*QROWS*DSTR*4);
  u16*   xall = (u16*)(ws + ubase);
  float* simb = (float*)(ws + ubase);
  float* Sbuf = (float*)(ws + A((size_t)64*QROWS*44*4));
  if(off > ws_size) return;

  k_wpack<<<dim3(11,10),256,0,stream>>>(Wu,Wb,Wt,Wd,Wp);
  k_gather<<<(XNR*80)/256,256,0,stream>>>(dwt,qwt,qet,det,emb,xall);
  k_bowpart<<<dim3(64,8,2),128,0,stream>>>(xall,parts);
  k_bowmat<<<dim3(64,2),128,0,stream>>>(parts,bowW,bowb,qbow,dbow);

  k_conv_mfma<<<dim3(64,8),512,0,stream>>>(xall,XDOC0,LD_,Wp,bu,bb,bt,dcat,(long)DSTR*128);
  k_conv_mfma<<<dim3(64,1),512,0,stream>>>(xall,XQ0,LQ_,Wp,bu,bb,bt,qcat,(long)QSTR*128);
  k_desc_mfma<<<80,512,0,stream>>>(xall,XQD0,Wp,bd,qdm);
  k_desc_mfma<<<160,512,0,stream>>>(xall,XDD0,Wp,bd,ddm);

  k_entpost<<<dim3(15,64),256,0,stream>>>(qei,qew,dei,dew,qdm,ddm,qbow,dbow,ent,car,qcat,dcat);
  k_sim_mfma<<<dim3(64,25),256,0,stream>>>(qcat,dcat,simb);
  k_gauss<<<dim3(64,QROWS),256,0,stream>>>(simb,dwm,dem,Sbuf);
  k_feats<<<64,256,0,stream>>>(Sbuf,qwm,qem,dfW,dfb,out);
}

// Round 6
// 171.833 us; speedup vs baseline: 2.2270x; 1.1669x over previous
//
#include <hip/hip_runtime.h>

typedef unsigned short u16;
typedef unsigned int u32;
typedef __attribute__((ext_vector_type(8))) short bf16x8;
typedef __attribute__((ext_vector_type(4))) float f32x4;

#define DEVI __device__ __forceinline__

namespace {
constexpr int LQ_ = 20, LD_ = 512, D_ = 300;
constexpr int EQ_ = 5, ED_ = 10, KC_ = 10;
constexpr int QROWS = 62, DROWS = 1543;
constexpr int QSTR = 64, DSTR = 1600;      // padded row strides for qcat/dcat/sim
// xall row regions (row index base), each row = 320 bf16 (zero-padded 300..319)
constexpr int XDOC0 = 0;          // 64*512
constexpr int XQ0   = 32768;      // 64*20
constexpr int XQD0  = 34048;      // 320*20
constexpr int XDD0  = 40448;      // 640*20
constexpr int XNR   = 53248;
constexpr float MU_H[11] = {1.0f,0.9f,0.7f,0.5f,0.3f,0.1f,-0.1f,-0.3f,-0.5f,-0.7f,-0.9f};
}

__constant__ int P2QT_C[16] = {0,0,0,1,2,1,1,2,2,3,3,3,0,1,2,3};
__constant__ int P2DT_C[16] = {0,2,1,0,0,1,2,1,2,0,1,2,3,3,3,3};

DEVI u16 f2bf(float f){ union{float f;u32 u;} v; v.f=f; u32 r=(v.u+0x7fffu+((v.u>>16)&1u))>>16; return (u16)r; }
DEVI float bf2f(u16 h){ union{u32 u;float f;} v; v.u=((u32)h)<<16; return v.f; }

// ---------------- Weight pack: bf16 MFMA-fragment layout ----------------
// Wp[((ts*8+n0)*10+ks)*64+lane][8]; lane=kg*16+col ; val=W[o=n0*16+col][tap][d=ks*32+kg*8+j]
__global__ __launch_bounds__(256) void k_wpack(const float* __restrict__ Wu, const float* __restrict__ Wb,
                                               const float* __restrict__ Wt, const float* __restrict__ Wd,
                                               u16* __restrict__ Wp){
  const int ts = blockIdx.x, ks = blockIdx.y;
  const float* W; int kk, tap;
  if(ts==0){W=Wu;kk=1;tap=0;}
  else if(ts<3){W=Wb;kk=2;tap=ts-1;}
  else if(ts<6){W=Wt;kk=3;tap=ts-3;}
  else {W=Wd;kk=5;tap=ts-6;}
  for(int idx=threadIdx.x; idx<4096; idx+=256){
    int n0=idx>>9, lane=(idx>>3)&63, j=idx&7;
    int col=lane&15, kg=lane>>4;
    int d=ks*32+kg*8+j, o=n0*16+col;
    float v = (d<300)? W[((long)o*kk + tap)*300 + d] : 0.f;
    Wp[(((long)(ts*8+n0)*10+ks)*64 + lane)*8 + j] = f2bf(v);
  }
}

// ---------------- One-shot gather: all token rows -> bf16 xall (row stride 320) ----------------
__global__ __launch_bounds__(256) void k_gather(const int* __restrict__ dwt, const int* __restrict__ qwt,
                                                const int* __restrict__ qet, const int* __restrict__ det,
                                                const float* __restrict__ emb, u16* __restrict__ xall){
  long idx = (long)blockIdx.x*256 + threadIdx.x;
  int row = (int)(idx/80), q = (int)(idx - (long)row*80);
  int tid;
  if(row < XQ0) tid = dwt[row];
  else if(row < XQD0) tid = qwt[row-XQ0];
  else if(row < XDD0) tid = qet[row-XQD0];
  else tid = det[row-XDD0];
  ushort4 o4;
  if(q < 75){
    float4 v = ((const float4*)(emb + (long)tid*D_))[q];
    o4.x=f2bf(v.x); o4.y=f2bf(v.y); o4.z=f2bf(v.z); o4.w=f2bf(v.w);
  } else { o4.x=0;o4.y=0;o4.z=0;o4.w=0; }
  *(ushort4*)(xall + (long)row*320 + q*4) = o4;
}

// ---------------- BOW phase A: partial sums from bf16 xall ----------------
__global__ __launch_bounds__(128) void k_bowpart(const u16* __restrict__ xall, float* __restrict__ partials){
  const int b=blockIdx.x, seg=blockIdx.y, side=blockIdx.z, t=threadIdx.x;
  float a0=0.f,a1=0.f,a2=0.f,a3=0.f;
  if(t<80){
    int nrow; long base;
    if(side==1){ nrow=64; base = ((long)b*LD_ + seg*64)*320; }
    else { nrow = (seg==0)? LQ_ : 0; base = ((long)XQ0 + b*LQ_)*320; }
    for(int r=0;r<nrow;r++){
      ushort4 v = *(const ushort4*)(xall + base + (long)r*320 + t*4);
      a0+=bf2f(v.x); a1+=bf2f(v.y); a2+=bf2f(v.z); a3+=bf2f(v.w);
    }
  }
  if(t<76){
    float4 o4={a0,a1,a2,a3};
    *(float4*)(partials + (((long)side*64 + b)*8 + seg)*304 + t*4) = o4;
  }
}

// ---------------- BOW phase B: reduce + matvec ----------------
__global__ __launch_bounds__(128) void k_bowmat(const float* __restrict__ partials,
                                                const float* __restrict__ bowW, const float* __restrict__ bowb,
                                                float* __restrict__ qbow, float* __restrict__ dbow){
  const int b=blockIdx.x, side=blockIdx.y, t=threadIdx.x;
  __shared__ float sv[304];
  const float* p = partials + ((long)side*64 + b)*8*304;
  for(int d=t; d<304; d+=128){
    float s=0.f;
    #pragma unroll
    for(int g=0;g<8;g++) s += p[g*304+d];
    sv[d]=s;
  }
  __syncthreads();
  float acc=0.f;
  const float* w = bowW + (long)t*D_;
  for(int d=0; d<D_; d++) acc += sv[d]*w[d];
  const float L = side? (float)LD_ : (float)LQ_;
  (side? dbow:qbow)[b*128+t] = acc + L*bowb[t];
}

// ---------------- uni/bi/tri conv via MFMA, weights-in-registers, 8-wave blocks ----------------
// wave w owns channel group n0=w. Weights loaded once per K-half; A streams from LDS.
__global__ __launch_bounds__(512) void k_conv_mfma(const u16* __restrict__ xall, int rowbase, int Ltok,
    const u16* __restrict__ Wp,
    const float* __restrict__ bu, const float* __restrict__ bb, const float* __restrict__ bt,
    u16* __restrict__ outp, long seqstride)
{
  const int seq=blockIdx.x, l0=blockIdx.y*64;
  const int t=threadIdx.x;
  __shared__ u16 xs[66*328];
  __shared__ float ot[64*130];
  const int nrows = min(66, Ltok - l0);
  const u16* src = xall + ((long)(rowbase + seq*Ltok + l0))*320;
  {
    const bf16x8 z = {0,0,0,0,0,0,0,0};
    for(int idx=t; idx<66*40; idx+=512){
      int r=idx/40, cc=idx-r*40;
      bf16x8 v = *(const bf16x8*)&src[(long)r*320 + cc*8];
      *(bf16x8*)&xs[r*328 + cc*8] = (r<nrows)? v : z;
    }
  }
  __syncthreads();
  const int lane=t&63, wave=t>>6;
  const int col16=lane&15, kg=lane>>4;
  #pragma unroll
  for(int c=0;c<3;c++){
    const int tb = (c==0)?0:((c==1)?1:3);
    const int base = (c==0)?0:((c==1)?Ltok:2*Ltok-1);
    const float* bias = (c==0)?bu:((c==1)?bb:bt);
    f32x4 acc4[4];
    #pragma unroll
    for(int mt=0;mt<4;mt++) acc4[mt]=(f32x4){0.f,0.f,0.f,0.f};
    #pragma unroll
    for(int h=0;h<2;h++){
      bf16x8 wf[15];
      #pragma unroll
      for(int i=0;i<=c;i++)
        #pragma unroll
        for(int k5=0;k5<5;k5++)
          wf[i*5+k5] = *(const bf16x8*)(Wp + (((long)((tb+i)*8 + wave)*10) + h*5 + k5)*512 + lane*8);
      #pragma unroll
      for(int mt=0;mt<4;mt++){
        #pragma unroll
        for(int i=0;i<=c;i++){
          const u16* xrow = &xs[(mt*16 + col16 + i)*328 + h*160];
          #pragma unroll
          for(int k5=0;k5<5;k5++){
            bf16x8 a = *(const bf16x8*)(xrow + k5*32 + kg*8);
            acc4[mt]=__builtin_amdgcn_mfma_f32_16x16x32_bf16(a,wf[i*5+k5],acc4[mt],0,0,0);
          }
        }
      }
    }
    const float bv = bias[wave*16+col16];
    #pragma unroll
    for(int mt=0;mt<4;mt++)
      #pragma unroll
      for(int reg=0;reg<4;reg++)
        ot[(mt*16+kg*4+reg)*130 + wave*16+col16] = fmaxf(acc4[mt][reg]+bv, 0.f);
    __syncthreads();
    // l2-norm + coalesced store
    {
      const int p = t>>3, j = t&7;
      const int nv = min(64, (Ltok - c) - l0);
      float ss=0.f;
      if(p<nv){
        #pragma unroll
        for(int k=0;k<16;k++){ float v = ot[p*130 + j + 8*k]; ss += v*v; }
      }
      ss += __shfl_xor(ss,1); ss += __shfl_xor(ss,2); ss += __shfl_xor(ss,4);
      if(p<nv){
        float inv = 1.0f/fmaxf(sqrtf(ss),1e-10f);
        u16* ob = outp + (long)seq*seqstride + ((long)(base + l0 + p))*128 + j*16;
        #pragma unroll
        for(int hh=0;hh<2;hh++){
          bf16x8 o8;
          #pragma unroll
          for(int e=0;e<8;e++) o8[e] = (short)f2bf(ot[p*130 + j*16 + hh*8 + e]*inv);
          *(bf16x8*)(ob + hh*8) = o8;
        }
      }
    }
    __syncthreads();
  }
}

// ---------------- Desc conv (k=5) via MFMA, weights-in-registers + fused max-pool ----------------
__global__ __launch_bounds__(512) void k_desc_mfma(const u16* __restrict__ xall, int rowbase,
    const u16* __restrict__ Wp, const float* __restrict__ bd, float* __restrict__ dm)
{
  const int t=threadIdx.x, lane=t&63, wave=t>>6;
  const int col16=lane&15, kg=lane>>4;
  __shared__ u16 xs4[4*20*328];
  {
    const int s0 = blockIdx.x*4;
    for(int idx=t; idx<4*20*40; idx+=512){
      int s=idx/800, rem=idx-s*800, r=rem/40, cc=rem-r*40;
      *(bf16x8*)&xs4[(s*20+r)*328 + cc*8] =
        *(const bf16x8*)&xall[((long)(rowbase + (s0+s)*20 + r))*320 + cc*8];
    }
  }
  __syncthreads();
  f32x4 acc4[4];
  #pragma unroll
  for(int s=0;s<4;s++) acc4[s]=(f32x4){0.f,0.f,0.f,0.f};
  #pragma unroll
  for(int h=0;h<2;h++){
    bf16x8 wf[25];
    #pragma unroll
    for(int tap=0;tap<5;tap++)
      #pragma unroll
      for(int k5=0;k5<5;k5++)
        wf[tap*5+k5] = *(const bf16x8*)(Wp + (((long)((6+tap)*8 + wave)*10) + h*5 + k5)*512 + lane*8);
    #pragma unroll
    for(int s=0;s<4;s++){
      #pragma unroll
      for(int tap=0;tap<5;tap++){
        const u16* xrow = &xs4[(s*20 + col16 + tap)*328 + h*160];
        #pragma unroll
        for(int k5=0;k5<5;k5++){
          bf16x8 a = *(const bf16x8*)(xrow + k5*32 + kg*8);
          acc4[s]=__builtin_amdgcn_mfma_f32_16x16x32_bf16(a,wf[tap*5+k5],acc4[s],0,0,0);
        }
      }
    }
  }
  const float bv = bd[wave*16+col16];
  #pragma unroll
  for(int s=0;s<4;s++){
    float m=-1e30f;
    #pragma unroll
    for(int reg=0;reg<4;reg++) m=fmaxf(m, acc4[s][reg]+bv);
    m=fmaxf(m,__shfl_xor(m,16));
    m=fmaxf(m,__shfl_xor(m,32));
    m=fmaxf(m,0.f);
    if(kg==0) dm[(long)(blockIdx.x*4+s)*128 + wave*16+col16]=m;
  }
}

// ---------------- Entity branch post: attention + combine + l2 ----------------
__global__ __launch_bounds__(256) void k_entpost(
    const int* __restrict__ qei, const int* __restrict__ qew,
    const int* __restrict__ dei, const int* __restrict__ dew,
    const float* __restrict__ qdm, const float* __restrict__ ddm,
    const float* __restrict__ qbow, const float* __restrict__ dbow,
    const float* __restrict__ ent, const float* __restrict__ car,
    u16* __restrict__ qcat, u16* __restrict__ dcat)
{
  const int e15 = blockIdx.x, b = blockIdx.y, t = threadIdx.x;
  const bool isq = (e15 < EQ_);
  const int e = isq? e15 : e15-EQ_;
  const float* dmx = isq? (qdm + (long)(b*EQ_+e)*128) : (ddm + (long)(b*ED_+e)*128);
  const float* bw = isq? (qbow + b*128) : (dbow + b*128);
  const int eid = isq? qei[b*EQ_+e] : dei[b*ED_+e];
  const int* carids = isq? (qew + b*EQ_*KC_ + e*KC_) : (dew + b*ED_*KC_ + e*KC_);
  u16* orow = isq? (qcat + ((long)b*QSTR + 57 + e)*128) : (dcat + ((long)b*DSTR + 1533 + e)*128);

  __shared__ float carS[KC_*128];
  __shared__ float sc[KC_], att[KC_];
  __shared__ float red[4];
  for(int idx=t; idx<KC_*128; idx+=256){
    int j = idx>>7, c = idx&127;
    carS[j*128+c] = car[(long)carids[j]*128 + c];
  }
  __syncthreads();
  {
    const int j = t>>4, l16 = t&15;
    if(j < KC_){
      float s=0.f;
      for(int c=l16;c<128;c+=16) s += bw[c]*carS[j*128+c];
      s += __shfl_xor(s,1); s += __shfl_xor(s,2); s += __shfl_xor(s,4); s += __shfl_xor(s,8);
      if(l16==0) sc[j]=s;
    }
  }
  __syncthreads();
  if(t==0){
    float m=-1e30f;
    for(int x=0;x<KC_;x++) m = fmaxf(m, sc[x]);
    float ssum=0.f;
    for(int x=0;x<KC_;x++){ float e2=__expf(sc[x]-m); att[x]=e2; ssum+=e2; }
    float rs = 1.0f/ssum;
    for(int x=0;x<KC_;x++) att[x]*=rs;
  }
  __syncthreads();
  float val=0.f;
  if(t<128){
    float ew=0.f;
    for(int x=0;x<KC_;x++) ew += att[x]*carS[x*128+t];
    val = ent[(long)eid*128+t] + dmx[t] + ew;
  }
  float ss = val*val;
  ss += __shfl_xor(ss,1); ss += __shfl_xor(ss,2); ss += __shfl_xor(ss,4);
  ss += __shfl_xor(ss,8); ss += __shfl_xor(ss,16); ss += __shfl_xor(ss,32);
  if((t&63)==0) red[t>>6]=ss;
  __syncthreads();
  if(t<128){
    float nv = 1.0f/fmaxf(sqrtf(red[0]+red[1]),1e-10f);
    orow[t] = f2bf(val*nv);
  }
}

// ---------------- sim = Qcat . Dcat^T via MFMA ----------------
__global__ __launch_bounds__(256) void k_sim_mfma(const u16* __restrict__ qcat, const u16* __restrict__ dcat,
                                                  float* __restrict__ sim){
  const int b=blockIdx.x, nb=blockIdx.y, t=threadIdx.x;
  __shared__ u16 Qs[64*136];
  __shared__ u16 Ds[64*136];
  const u16* qbase = qcat + (long)b*QSTR*128;
  const u16* dbase = dcat + ((long)b*DSTR + nb*64)*128;
  for(int idx=t; idx<1024; idx+=256){
    int r=idx>>4, c8=(idx&15)*8;
    *(bf16x8*)&Qs[r*136+c8] = *(const bf16x8*)&qbase[(long)r*128+c8];
    *(bf16x8*)&Ds[r*136+c8] = *(const bf16x8*)&dbase[(long)r*128+c8];
  }
  __syncthreads();
  const int lane=t&63, wave=t>>6, col16=lane&15, kg=lane>>4;
  f32x4 acc[4];
  #pragma unroll
  for(int n0=0;n0<4;n0++) acc[n0]=(f32x4){0.f,0.f,0.f,0.f};
  #pragma unroll
  for(int ks=0;ks<4;ks++){
    bf16x8 a=*(const bf16x8*)&Qs[(wave*16+col16)*136 + ks*32 + kg*8];
    #pragma unroll
    for(int n0=0;n0<4;n0++){
      bf16x8 bfr=*(const bf16x8*)&Ds[(n0*16+col16)*136 + ks*32 + kg*8];
      acc[n0]=__builtin_amdgcn_mfma_f32_16x16x32_bf16(a,bfr,acc[n0],0,0,0);
    }
  }
  #pragma unroll
  for(int n0=0;n0<4;n0++){
    const int col = nb*64 + n0*16 + col16;
    #pragma unroll
    for(int reg=0;reg<4;reg++){
      const int qr = wave*16 + kg*4 + reg;
      if(qr<QROWS) sim[((long)b*QROWS+qr)*DSTR + col]=acc[n0][reg];
    }
  }
}

// ---------------- RBF pools: wave-per-(b,qr), register accumulators ----------------
__global__ __launch_bounds__(512) void k_gauss(const float* __restrict__ sim, const float* __restrict__ dwm,
                                               const float* __restrict__ dem, float* __restrict__ S){
  const int b = blockIdx.x;
  const int wave = threadIdx.x>>6, lane = threadIdx.x&63;
  const int qr = blockIdx.y*8 + wave;
  if(qr >= QROWS) return;
  const float* srow = sim + ((long)b*QROWS + qr)*DSTR;
  float* Sout = S + ((long)b*QROWS + qr)*44;
  const float* dwmb = dwm + b*LD_;
  const float* demb = dem + b*ED_;
  constexpr int SBASE[4] = {0,512,1023,1533};
  constexpr int SLEN[4]  = {512,511,510,10};
  #pragma unroll
  for(int s=0;s<4;s++){
    const float* mask = (s<3)? dwmb : demb;
    float a[11];
    #pragma unroll
    for(int m=0;m<11;m++) a[m]=0.f;
    for(int i=lane; i<SLEN[s]; i+=64){
      float sv = srow[SBASE[s]+i];
      float md = mask[i];
      float d1 = sv - 1.0f;
      a[0] += md*__expf(-500000.0f*d1*d1);
      #pragma unroll
      for(int m=1;m<11;m++){ float dm = sv - MU_H[m]; a[m] += md*__expf(-50.0f*dm*dm); }
    }
    #pragma unroll
    for(int m=0;m<11;m++){
      float v=a[m];
      v+=__shfl_xor(v,1); v+=__shfl_xor(v,2); v+=__shfl_xor(v,4);
      v+=__shfl_xor(v,8); v+=__shfl_xor(v,16); v+=__shfl_xor(v,32);
      if(lane==0) Sout[s*11+m]=v;
    }
  }
}

// ---------------- log-pool + dense + tanh ----------------
__global__ __launch_bounds__(256) void k_feats(const float* __restrict__ S, const float* __restrict__ qwm,
                                               const float* __restrict__ qem, const float* __restrict__ dfW,
                                               const float* __restrict__ dfb, float* __restrict__ out){
  const int b = blockIdx.x, t = threadIdx.x;
  __shared__ float fsh[176];
  __shared__ float red[4];
  if(t<176){
    const int pool = t/11, m = t - pool*11;
    const int qt = P2QT_C[pool], dt = P2DT_C[pool];
    const int qlo = (qt==0)?0:((qt==1)?20:((qt==2)?39:57));
    const int qn  = (qt==0)?20:((qt==1)?19:((qt==2)?18:5));
    const float* Sb = S + ((long)b*QROWS)*44 + dt*11 + m;
    float f = 0.f;
    for(int r=0;r<qn;r++){
      float mq = (qt<3)? qwm[b*LQ_+r] : qem[b*EQ_+r];
      float sv = Sb[(long)(qlo+r)*44];
      f += logf(fmaxf(sv,1e-10f))*0.01f*mq;
    }
    fsh[t] = f;
  }
  __syncthreads();
  float v = (t<176)? fsh[t]*dfW[t] : 0.f;
  v += __shfl_xor(v,1); v += __shfl_xor(v,2); v += __shfl_xor(v,4);
  v += __shfl_xor(v,8); v += __shfl_xor(v,16); v += __shfl_xor(v,32);
  if((t&63)==0) red[t>>6]=v;
  __syncthreads();
  if(t==0) out[b] = tanhf(red[0]+red[1]+red[2]+red[3] + dfb[0]);
}

extern "C" void kernel_launch(void* const* d_in, const int* in_sizes, int n_in,
                              void* d_out, int out_size, void* d_ws, size_t ws_size,
                              hipStream_t stream)
{
  const int*   qwt=(const int*)d_in[0];
  const float* qwm=(const float*)d_in[1];
  const int*   qei=(const int*)d_in[2];
  const int*   qet=(const int*)d_in[3];
  const int*   qew=(const int*)d_in[4];
  const float* qem=(const float*)d_in[5];
  const int*   dwt=(const int*)d_in[6];
  const float* dwm=(const float*)d_in[7];
  const int*   dei=(const int*)d_in[8];
  const int*   det=(const int*)d_in[9];
  const int*   dew=(const int*)d_in[10];
  const float* dem=(const float*)d_in[11];
  const float* emb=(const float*)d_in[12];
  const float* ent=(const float*)d_in[13];
  const float* car=(const float*)d_in[14];
  const float* bowW=(const float*)d_in[15];
  const float* bowb=(const float*)d_in[16];
  const float* Wu=(const float*)d_in[17];
  const float* bu=(const float*)d_in[18];
  const float* Wb=(const float*)d_in[19];
  const float* bb=(const float*)d_in[20];
  const float* Wt=(const float*)d_in[21];
  const float* bt=(const float*)d_in[22];
  const float* Wd=(const float*)d_in[23];
  const float* bd=(const float*)d_in[24];
  const float* dfW=(const float*)d_in[25];
  const float* dfb=(const float*)d_in[26];
  float* out=(float*)d_out;

  char* ws=(char*)d_ws;
  size_t off=0;
  auto A=[&](size_t n){ size_t r=off; off=(off+n+255)&~(size_t)255; return r; };
  u16* Wp     = (u16*)(ws + A((size_t)11*8*10*64*8*2));
  u16* dcat   = (u16*)(ws + A((size_t)64*DSTR*128*2));
  u16* qcat   = (u16*)(ws + A((size_t)64*QSTR*128*2));
  float* qdm  = (float*)(ws + A((size_t)320*128*4));
  float* ddm  = (float*)(ws + A((size_t)640*128*4));
  float* parts= (float*)(ws + A((size_t)2*64*8*304*4));
  float* qbow = (float*)(ws + A((size_t)64*128*4));
  float* dbow = (float*)(ws + A((size_t)64*128*4));
  // union: xall (gather staging, used through conv/desc/bow) overlaps simb (written later)
  size_t ubase = A((size_t)XNR*320*2 > (size_t)64*QROWS*DSTR*4 ? (size_t)XNR*320*2 : (size_t)64*QROWS*DSTR*4);
  u16*   xall = (u16*)(ws + ubase);
  float* simb = (float*)(ws + ubase);
  float* Sbuf = (float*)(ws + A((size_t)64*QROWS*44*4));
  if(off > ws_size) return;

  k_wpack<<<dim3(11,10),256,0,stream>>>(Wu,Wb,Wt,Wd,Wp);
  k_gather<<<(XNR*80)/256,256,0,stream>>>(dwt,qwt,qet,det,emb,xall);
  k_bowpart<<<dim3(64,8,2),128,0,stream>>>(xall,parts);
  k_bowmat<<<dim3(64,2),128,0,stream>>>(parts,bowW,bowb,qbow,dbow);

  k_conv_mfma<<<dim3(64,8),512,0,stream>>>(xall,XDOC0,LD_,Wp,bu,bb,bt,dcat,(long)DSTR*128);
  k_conv_mfma<<<dim3(64,1),512,0,stream>>>(xall,XQ0,LQ_,Wp,bu,bb,bt,qcat,(long)QSTR*128);
  k_desc_mfma<<<80,512,0,stream>>>(xall,XQD0,Wp,bd,qdm);
  k_desc_mfma<<<160,512,0,stream>>>(xall,XDD0,Wp,bd,ddm);

  k_entpost<<<dim3(15,64),256,0,stream>>>(qei,qew,dei,dew,qdm,ddm,qbow,dbow,ent,car,qcat,dcat);
  k_sim_mfma<<<dim3(64,25),256,0,stream>>>(qcat,dcat,simb);
  k_gauss<<<dim3(64,8),512,0,stream>>>(simb,dwm,dem,Sbuf);
  k_feats<<<64,256,0,stream>>>(Sbuf,qwm,qem,dfW,dfb,out);
}